// Round 3
// baseline (1376.246 us; speedup 1.0000x reference)
//
#include <hip/hip_runtime.h>
#include <math.h>

#define NT  256
#define SPB 84      // samples per block: 42 pairs x 6 node-threads = 252 active threads

// ---- LDS float offsets ----
#define O_REC  0      // 512:  per-h 16: A[6], Bm[6], c0, w2, pad2
#define O_WD1  512    // 192   [m][o] 6x32
#define O_BD1  704    // 32
#define O_WD2  736    // 1024  [k][o] 32x32
#define O_BD2  1760   // 32
#define O_WD3T 1792   // 192   [j][k] transposed 6x32
#define O_BD3  1984   // 8 (6 used)
#define O_WS1  1992   // 576   [m][o] 18x32
#define O_BS1  2568   // 32
#define O_WS2  2600   // 512   [k][o] 32x16
#define O_BS2  3112   // 16
#define O_WS3  3128   // 16
#define O_MISC 3144   // [0]=bs3, [1]=be2
#define W_TOT  3148

__device__ __forceinline__ float sigmoidf_(float x) {
    return 1.0f / (1.0f + __expf(-x));
}

__global__ __launch_bounds__(NT, 3) void fused2_kernel(
        const float* __restrict__ factors,
        const float* __restrict__ Wn,  const float* __restrict__ bn,
        const float* __restrict__ We1, const float* __restrict__ be1,
        const float* __restrict__ We2, const float* __restrict__ be2,
        const float* __restrict__ Wd1, const float* __restrict__ bd1,
        const float* __restrict__ Wd2, const float* __restrict__ bd2,
        const float* __restrict__ Wd3, const float* __restrict__ bd3,
        const float* __restrict__ Ws1, const float* __restrict__ bs1,
        const float* __restrict__ Ws2, const float* __restrict__ bs2,
        const float* __restrict__ Ws3, const float* __restrict__ bs3,
        float* __restrict__ adj_out, float* __restrict__ pred_out,
        float* __restrict__ scores, int B) {
    __shared__ float Wsh[W_TOT];
    __shared__ float adj_s[SPB * 6 * 8];   // padded rows of 8 for aligned float4
    __shared__ float sc_s[SPB * 6];

    const int t = threadIdx.x;
    const int p = t / 6;          // pair index 0..41 (for t<252)
    const int n = t - p * 6;      // node row 0..5
    const int b0 = blockIdx.x * SPB + 2 * p;
    const int b1 = b0 + 1;
    const bool act = (t < (SPB / 2) * 6);     // 252
    const bool a0 = act && (b0 < B);
    const bool a1 = act && (b1 < B);
    const int s0l = 2 * p, s1l = 2 * p + 1;

    // ---- factor prefetch (registers), issued before fold so latency overlaps ----
    float fall0[36], fall1[36], fi0[6], fi1[6];
    #pragma unroll
    for (int q = 0; q < 36; ++q) { fall0[q] = 0.f; fall1[q] = 0.f; }
    #pragma unroll
    for (int m = 0; m < 6; ++m) { fi0[m] = 0.f; fi1[m] = 0.f; }
    if (a0) {
        const float* f = factors + (size_t)b0 * 36;
        #pragma unroll
        for (int q = 0; q < 9; ++q) {
            float4 v = reinterpret_cast<const float4*>(f)[q];
            fall0[q*4+0] = v.x; fall0[q*4+1] = v.y; fall0[q*4+2] = v.z; fall0[q*4+3] = v.w;
        }
        #pragma unroll
        for (int m = 0; m < 6; ++m) fi0[m] = f[n*6 + m];
    }
    if (a1) {
        const float* f = factors + (size_t)b1 * 36;
        #pragma unroll
        for (int q = 0; q < 9; ++q) {
            float4 v = reinterpret_cast<const float4*>(f)[q];
            fall1[q*4+0] = v.x; fall1[q*4+1] = v.y; fall1[q*4+2] = v.z; fall1[q*4+3] = v.w;
        }
        #pragma unroll
        for (int m = 0; m < 6; ++m) fi1[m] = f[n*6 + m];
    }

    // ---- inline fold: rec[512] into LDS (2 entries/thread) ----
    #pragma unroll
    for (int e0 = 0; e0 < 512; e0 += NT) {
        int e = e0 + t;
        int h = e >> 4, sl = e & 15;
        float val = 0.0f;
        if (sl < 6) {
            #pragma unroll
            for (int k = 0; k < 32; ++k) val = fmaf(Wn[sl*32+k], We1[k*32+h], val);
        } else if (sl < 12) {
            int m = sl - 6;
            #pragma unroll
            for (int k = 0; k < 32; ++k) val = fmaf(Wn[m*32+k], We1[(32+k)*32+h], val);
        } else if (sl == 12) {
            #pragma unroll
            for (int k = 0; k < 32; ++k) val = fmaf(bn[k], We1[k*32+h] + We1[(32+k)*32+h], val);
            val += be1[h];
        } else if (sl == 13) {
            val = We2[h];
        }
        Wsh[O_REC + e] = val;
    }
    // ---- stage dyn/scorer weights ----
    for (int i = t; i < 192;  i += NT) Wsh[O_WD1 + i] = Wd1[i];
    for (int i = t; i < 1024; i += NT) Wsh[O_WD2 + i] = Wd2[i];
    for (int i = t; i < 192;  i += NT) { int j = i >> 5, k = i & 31; Wsh[O_WD3T + i] = Wd3[k*6 + j]; }
    for (int i = t; i < 576;  i += NT) Wsh[O_WS1 + i] = Ws1[i];
    for (int i = t; i < 512;  i += NT) Wsh[O_WS2 + i] = Ws2[i];
    if (t < 32) Wsh[O_BD1 + t] = bd1[t];
    if (t < 32) Wsh[O_BD2 + t] = bd2[t];
    if (t < 6)  Wsh[O_BD3 + t] = bd3[t];
    if (t < 32) Wsh[O_BS1 + t] = bs1[t];
    if (t < 16) Wsh[O_BS2 + t] = bs2[t];
    if (t < 16) Wsh[O_WS3 + t] = Ws3[t];
    if (t == 0) { Wsh[O_MISC] = bs3[0]; Wsh[O_MISC + 1] = be2[0]; }
    __syncthreads();

    // ================= edge phase =================
    if (act) {
        float acc0[6] = {0.f,0.f,0.f,0.f,0.f,0.f};
        float acc1[6] = {0.f,0.f,0.f,0.f,0.f,0.f};
        #pragma unroll
        for (int h = 0; h < 32; ++h) {
            const float4 r0 = *reinterpret_cast<const float4*>(&Wsh[O_REC + h*16 + 0]);
            const float4 r1 = *reinterpret_cast<const float4*>(&Wsh[O_REC + h*16 + 4]);
            const float4 r2 = *reinterpret_cast<const float4*>(&Wsh[O_REC + h*16 + 8]);
            const float4 r3 = *reinterpret_cast<const float4*>(&Wsh[O_REC + h*16 + 12]);
            float uh0 = r3.x, uh1 = r3.x;
            uh0 = fmaf(fi0[0], r0.x, uh0); uh1 = fmaf(fi1[0], r0.x, uh1);
            uh0 = fmaf(fi0[1], r0.y, uh0); uh1 = fmaf(fi1[1], r0.y, uh1);
            uh0 = fmaf(fi0[2], r0.z, uh0); uh1 = fmaf(fi1[2], r0.z, uh1);
            uh0 = fmaf(fi0[3], r0.w, uh0); uh1 = fmaf(fi1[3], r0.w, uh1);
            uh0 = fmaf(fi0[4], r1.x, uh0); uh1 = fmaf(fi1[4], r1.x, uh1);
            uh0 = fmaf(fi0[5], r1.y, uh0); uh1 = fmaf(fi1[5], r1.y, uh1);
            const float w2 = r3.y;
            #pragma unroll
            for (int j = 0; j < 6; ++j) {
                float v0 =      fall0[j*6+0] * r1.z;
                v0 = fmaf(fall0[j*6+1], r1.w, v0);
                v0 = fmaf(fall0[j*6+2], r2.x, v0);
                v0 = fmaf(fall0[j*6+3], r2.y, v0);
                v0 = fmaf(fall0[j*6+4], r2.z, v0);
                v0 = fmaf(fall0[j*6+5], r2.w, v0);
                float v1 =      fall1[j*6+0] * r1.z;
                v1 = fmaf(fall1[j*6+1], r1.w, v1);
                v1 = fmaf(fall1[j*6+2], r2.x, v1);
                v1 = fmaf(fall1[j*6+3], r2.y, v1);
                v1 = fmaf(fall1[j*6+4], r2.z, v1);
                v1 = fmaf(fall1[j*6+5], r2.w, v1);
                acc0[j] = fmaf(fmaxf(uh0 + v0, 0.f), w2, acc0[j]);
                acc1[j] = fmaf(fmaxf(uh1 + v1, 0.f), w2, acc1[j]);
            }
        }
        const float b2 = Wsh[O_MISC + 1];
        float av0[6], av1[6];
        #pragma unroll
        for (int j = 0; j < 6; ++j) {
            av0[j] = (j == n) ? 0.f : sigmoidf_(acc0[j] + b2);
            av1[j] = (j == n) ? 0.f : sigmoidf_(acc1[j] + b2);
        }
        if (a0) {
            float* ao = adj_out + (size_t)b0 * 36 + n * 6;
            *reinterpret_cast<float2*>(&ao[0]) = make_float2(av0[0], av0[1]);
            *reinterpret_cast<float2*>(&ao[2]) = make_float2(av0[2], av0[3]);
            *reinterpret_cast<float2*>(&ao[4]) = make_float2(av0[4], av0[5]);
            float* as = &adj_s[(s0l*6 + n) * 8];
            *reinterpret_cast<float4*>(&as[0]) = make_float4(av0[0], av0[1], av0[2], av0[3]);
            *reinterpret_cast<float2*>(&as[4]) = make_float2(av0[4], av0[5]);
        }
        if (a1) {
            float* ao = adj_out + (size_t)b1 * 36 + n * 6;
            *reinterpret_cast<float2*>(&ao[0]) = make_float2(av1[0], av1[1]);
            *reinterpret_cast<float2*>(&ao[2]) = make_float2(av1[2], av1[3]);
            *reinterpret_cast<float2*>(&ao[4]) = make_float2(av1[4], av1[5]);
            float* as = &adj_s[(s1l*6 + n) * 8];
            *reinterpret_cast<float4*>(&as[0]) = make_float4(av1[0], av1[1], av1[2], av1[3]);
            *reinterpret_cast<float2*>(&as[4]) = make_float2(av1[4], av1[5]);
        }
    }
    __syncthreads();

    // ================= dynamics + scorer =================
    if (act) {
        // structured[n][i] = sum_j adj[i][j] * fi[j]
        float st0[6], st1[6];
        #pragma unroll
        for (int i = 0; i < 6; ++i) {
            const float4 qa = *reinterpret_cast<const float4*>(&adj_s[(s0l*6 + i) * 8]);
            const float2 qb = *reinterpret_cast<const float2*>(&adj_s[(s0l*6 + i) * 8 + 4]);
            float v = fi0[0] * qa.x;
            v = fmaf(fi0[1], qa.y, v); v = fmaf(fi0[2], qa.z, v);
            v = fmaf(fi0[3], qa.w, v); v = fmaf(fi0[4], qb.x, v);
            v = fmaf(fi0[5], qb.y, v);
            st0[i] = v;
            const float4 ra = *reinterpret_cast<const float4*>(&adj_s[(s1l*6 + i) * 8]);
            const float2 rb = *reinterpret_cast<const float2*>(&adj_s[(s1l*6 + i) * 8 + 4]);
            float w = fi1[0] * ra.x;
            w = fmaf(fi1[1], ra.y, w); w = fmaf(fi1[2], ra.z, w);
            w = fmaf(fi1[3], ra.w, w); w = fmaf(fi1[4], rb.x, w);
            w = fmaf(fi1[5], rb.y, w);
            st1[i] = w;
        }

        // h1 = relu(st @ Wd1 + bd1)
        float h1a[32], h1b[32];
        #pragma unroll
        for (int o4 = 0; o4 < 8; ++o4) {
            const float4 v = *reinterpret_cast<const float4*>(&Wsh[O_BD1 + o4*4]);
            h1a[o4*4+0] = v.x; h1a[o4*4+1] = v.y; h1a[o4*4+2] = v.z; h1a[o4*4+3] = v.w;
            h1b[o4*4+0] = v.x; h1b[o4*4+1] = v.y; h1b[o4*4+2] = v.z; h1b[o4*4+3] = v.w;
        }
        #pragma unroll
        for (int m = 0; m < 6; ++m) {
            const float sa = st0[m], sb = st1[m];
            #pragma unroll
            for (int o4 = 0; o4 < 8; ++o4) {
                const float4 w = *reinterpret_cast<const float4*>(&Wsh[O_WD1 + m*32 + o4*4]);
                h1a[o4*4+0] = fmaf(sa, w.x, h1a[o4*4+0]); h1b[o4*4+0] = fmaf(sb, w.x, h1b[o4*4+0]);
                h1a[o4*4+1] = fmaf(sa, w.y, h1a[o4*4+1]); h1b[o4*4+1] = fmaf(sb, w.y, h1b[o4*4+1]);
                h1a[o4*4+2] = fmaf(sa, w.z, h1a[o4*4+2]); h1b[o4*4+2] = fmaf(sb, w.z, h1b[o4*4+2]);
                h1a[o4*4+3] = fmaf(sa, w.w, h1a[o4*4+3]); h1b[o4*4+3] = fmaf(sb, w.w, h1b[o4*4+3]);
            }
        }
        #pragma unroll
        for (int o = 0; o < 32; ++o) { h1a[o] = fmaxf(h1a[o], 0.f); h1b[o] = fmaxf(h1b[o], 0.f); }

        // h2 = relu(h1 @ Wd2 + bd2)
        float h2a[32], h2b[32];
        #pragma unroll
        for (int o4 = 0; o4 < 8; ++o4) {
            const float4 v = *reinterpret_cast<const float4*>(&Wsh[O_BD2 + o4*4]);
            h2a[o4*4+0] = v.x; h2a[o4*4+1] = v.y; h2a[o4*4+2] = v.z; h2a[o4*4+3] = v.w;
            h2b[o4*4+0] = v.x; h2b[o4*4+1] = v.y; h2b[o4*4+2] = v.z; h2b[o4*4+3] = v.w;
        }
        #pragma unroll
        for (int k = 0; k < 32; ++k) {
            const float xa = h1a[k], xb = h1b[k];
            #pragma unroll
            for (int o4 = 0; o4 < 8; ++o4) {
                const float4 w = *reinterpret_cast<const float4*>(&Wsh[O_WD2 + k*32 + o4*4]);
                h2a[o4*4+0] = fmaf(xa, w.x, h2a[o4*4+0]); h2b[o4*4+0] = fmaf(xb, w.x, h2b[o4*4+0]);
                h2a[o4*4+1] = fmaf(xa, w.y, h2a[o4*4+1]); h2b[o4*4+1] = fmaf(xb, w.y, h2b[o4*4+1]);
                h2a[o4*4+2] = fmaf(xa, w.z, h2a[o4*4+2]); h2b[o4*4+2] = fmaf(xb, w.z, h2b[o4*4+2]);
                h2a[o4*4+3] = fmaf(xa, w.w, h2a[o4*4+3]); h2b[o4*4+3] = fmaf(xb, w.w, h2b[o4*4+3]);
            }
        }
        #pragma unroll
        for (int o = 0; o < 32; ++o) { h2a[o] = fmaxf(h2a[o], 0.f); h2b[o] = fmaxf(h2b[o], 0.f); }

        // pred = h2 @ Wd3 + bd3  (Wd3 transposed in LDS: [j][k])
        float pra[6], prb[6];
        #pragma unroll
        for (int j = 0; j < 6; ++j) {
            float va = Wsh[O_BD3 + j], vb = va;
            #pragma unroll
            for (int k4 = 0; k4 < 8; ++k4) {
                const float4 w = *reinterpret_cast<const float4*>(&Wsh[O_WD3T + j*32 + k4*4]);
                va = fmaf(h2a[k4*4+0], w.x, va); vb = fmaf(h2b[k4*4+0], w.x, vb);
                va = fmaf(h2a[k4*4+1], w.y, va); vb = fmaf(h2b[k4*4+1], w.y, vb);
                va = fmaf(h2a[k4*4+2], w.z, va); vb = fmaf(h2b[k4*4+2], w.z, vb);
                va = fmaf(h2a[k4*4+3], w.w, va); vb = fmaf(h2b[k4*4+3], w.w, vb);
            }
            pra[j] = va; prb[j] = vb;
        }
        if (a0) {
            float* po = pred_out + (size_t)b0 * 36 + n * 6;
            *reinterpret_cast<float2*>(&po[0]) = make_float2(pra[0], pra[1]);
            *reinterpret_cast<float2*>(&po[2]) = make_float2(pra[2], pra[3]);
            *reinterpret_cast<float2*>(&po[4]) = make_float2(pra[4], pra[5]);
        }
        if (a1) {
            float* po = pred_out + (size_t)b1 * 36 + n * 6;
            *reinterpret_cast<float2*>(&po[0]) = make_float2(prb[0], prb[1]);
            *reinterpret_cast<float2*>(&po[2]) = make_float2(prb[2], prb[3]);
            *reinterpret_cast<float2*>(&po[4]) = make_float2(prb[4], prb[5]);
        }

        float dfa[6], dfb[6];
        #pragma unroll
        for (int j = 0; j < 6; ++j) { dfa[j] = fabsf(fi0[j] - pra[j]); dfb[j] = fabsf(fi1[j] - prb[j]); }

        // s1 = relu([fi,pr,df] @ Ws1 + bs1)
        float s1a[32], s1b[32];
        #pragma unroll
        for (int o4 = 0; o4 < 8; ++o4) {
            const float4 v = *reinterpret_cast<const float4*>(&Wsh[O_BS1 + o4*4]);
            s1a[o4*4+0] = v.x; s1a[o4*4+1] = v.y; s1a[o4*4+2] = v.z; s1a[o4*4+3] = v.w;
            s1b[o4*4+0] = v.x; s1b[o4*4+1] = v.y; s1b[o4*4+2] = v.z; s1b[o4*4+3] = v.w;
        }
        #pragma unroll
        for (int m = 0; m < 6; ++m) {
            const float aa = fi0[m], pa = pra[m], da = dfa[m];
            const float ab = fi1[m], pb = prb[m], db = dfb[m];
            #pragma unroll
            for (int o4 = 0; o4 < 8; ++o4) {
                const float4 wa = *reinterpret_cast<const float4*>(&Wsh[O_WS1 + m*32 + o4*4]);
                const float4 wp = *reinterpret_cast<const float4*>(&Wsh[O_WS1 + (6+m)*32 + o4*4]);
                const float4 wd = *reinterpret_cast<const float4*>(&Wsh[O_WS1 + (12+m)*32 + o4*4]);
                s1a[o4*4+0] = fmaf(aa, wa.x, fmaf(pa, wp.x, fmaf(da, wd.x, s1a[o4*4+0])));
                s1b[o4*4+0] = fmaf(ab, wa.x, fmaf(pb, wp.x, fmaf(db, wd.x, s1b[o4*4+0])));
                s1a[o4*4+1] = fmaf(aa, wa.y, fmaf(pa, wp.y, fmaf(da, wd.y, s1a[o4*4+1])));
                s1b[o4*4+1] = fmaf(ab, wa.y, fmaf(pb, wp.y, fmaf(db, wd.y, s1b[o4*4+1])));
                s1a[o4*4+2] = fmaf(aa, wa.z, fmaf(pa, wp.z, fmaf(da, wd.z, s1a[o4*4+2])));
                s1b[o4*4+2] = fmaf(ab, wa.z, fmaf(pb, wp.z, fmaf(db, wd.z, s1b[o4*4+2])));
                s1a[o4*4+3] = fmaf(aa, wa.w, fmaf(pa, wp.w, fmaf(da, wd.w, s1a[o4*4+3])));
                s1b[o4*4+3] = fmaf(ab, wa.w, fmaf(pb, wp.w, fmaf(db, wd.w, s1b[o4*4+3])));
            }
        }
        #pragma unroll
        for (int o = 0; o < 32; ++o) { s1a[o] = fmaxf(s1a[o], 0.f); s1b[o] = fmaxf(s1b[o], 0.f); }

        // s2 = relu(s1 @ Ws2 + bs2)
        float s2a[16], s2b[16];
        #pragma unroll
        for (int o4 = 0; o4 < 4; ++o4) {
            const float4 v = *reinterpret_cast<const float4*>(&Wsh[O_BS2 + o4*4]);
            s2a[o4*4+0] = v.x; s2a[o4*4+1] = v.y; s2a[o4*4+2] = v.z; s2a[o4*4+3] = v.w;
            s2b[o4*4+0] = v.x; s2b[o4*4+1] = v.y; s2b[o4*4+2] = v.z; s2b[o4*4+3] = v.w;
        }
        #pragma unroll
        for (int k = 0; k < 32; ++k) {
            const float xa = s1a[k], xb = s1b[k];
            #pragma unroll
            for (int o4 = 0; o4 < 4; ++o4) {
                const float4 w = *reinterpret_cast<const float4*>(&Wsh[O_WS2 + k*16 + o4*4]);
                s2a[o4*4+0] = fmaf(xa, w.x, s2a[o4*4+0]); s2b[o4*4+0] = fmaf(xb, w.x, s2b[o4*4+0]);
                s2a[o4*4+1] = fmaf(xa, w.y, s2a[o4*4+1]); s2b[o4*4+1] = fmaf(xb, w.y, s2b[o4*4+1]);
                s2a[o4*4+2] = fmaf(xa, w.z, s2a[o4*4+2]); s2b[o4*4+2] = fmaf(xb, w.z, s2b[o4*4+2]);
                s2a[o4*4+3] = fmaf(xa, w.w, s2a[o4*4+3]); s2b[o4*4+3] = fmaf(xb, w.w, s2b[o4*4+3]);
            }
        }
        #pragma unroll
        for (int o = 0; o < 16; ++o) { s2a[o] = fmaxf(s2a[o], 0.f); s2b[o] = fmaxf(s2b[o], 0.f); }

        // s3 = sigmoid(s2 @ Ws3 + bs3)
        float s3a = Wsh[O_MISC], s3b = s3a;
        #pragma unroll
        for (int k4 = 0; k4 < 4; ++k4) {
            const float4 w = *reinterpret_cast<const float4*>(&Wsh[O_WS3 + k4*4]);
            s3a = fmaf(s2a[k4*4+0], w.x, s3a); s3b = fmaf(s2b[k4*4+0], w.x, s3b);
            s3a = fmaf(s2a[k4*4+1], w.y, s3a); s3b = fmaf(s2b[k4*4+1], w.y, s3b);
            s3a = fmaf(s2a[k4*4+2], w.z, s3a); s3b = fmaf(s2b[k4*4+2], w.z, s3b);
            s3a = fmaf(s2a[k4*4+3], w.w, s3a); s3b = fmaf(s2b[k4*4+3], w.w, s3b);
        }
        sc_s[s0l*6 + n] = sigmoidf_(s3a);
        sc_s[s1l*6 + n] = sigmoidf_(s3b);
    }
    __syncthreads();

    if (act && n == 0) {
        if (a0) {
            float sum = sc_s[s0l*6+0] + sc_s[s0l*6+1] + sc_s[s0l*6+2]
                      + sc_s[s0l*6+3] + sc_s[s0l*6+4] + sc_s[s0l*6+5];
            scores[b0] = sum * (1.0f / 6.0f);
        }
        if (a1) {
            float sum = sc_s[s1l*6+0] + sc_s[s1l*6+1] + sc_s[s1l*6+2]
                      + sc_s[s1l*6+3] + sc_s[s1l*6+4] + sc_s[s1l*6+5];
            scores[b1] = sum * (1.0f / 6.0f);
        }
    }
}

extern "C" void kernel_launch(void* const* d_in, const int* in_sizes, int n_in,
                              void* d_out, int out_size, void* d_ws, size_t ws_size,
                              hipStream_t stream) {
    const float* factors = (const float*)d_in[0];
    const float* Wn  = (const float*)d_in[1];
    const float* bn  = (const float*)d_in[2];
    const float* We1 = (const float*)d_in[3];
    const float* be1 = (const float*)d_in[4];
    const float* We2 = (const float*)d_in[5];
    const float* be2 = (const float*)d_in[6];
    const float* Wd1 = (const float*)d_in[7];
    const float* bd1 = (const float*)d_in[8];
    const float* Wd2 = (const float*)d_in[9];
    const float* bd2 = (const float*)d_in[10];
    const float* Wd3 = (const float*)d_in[11];
    const float* bd3 = (const float*)d_in[12];
    const float* Ws1 = (const float*)d_in[13];
    const float* bs1 = (const float*)d_in[14];
    const float* Ws2 = (const float*)d_in[15];
    const float* bs2 = (const float*)d_in[16];
    const float* Ws3 = (const float*)d_in[17];
    const float* bs3 = (const float*)d_in[18];

    int B = in_sizes[0] / 36;

    float* adj_out  = (float*)d_out;                       // [B,6,6]
    float* pred_out = (float*)d_out + (size_t)B * 36;      // [B,6,6]
    float* scores   = (float*)d_out + (size_t)B * 72;      // [B]

    int nblocks = (B + SPB - 1) / SPB;
    hipLaunchKernelGGL(fused2_kernel, dim3(nblocks), dim3(NT), 0, stream,
                       factors, Wn, bn, We1, be1, We2, be2,
                       Wd1, bd1, Wd2, bd2, Wd3, bd3,
                       Ws1, bs1, Ws2, bs2, Ws3, bs3,
                       adj_out, pred_out, scores, B);
}

// Round 4
// 179.746 us; speedup vs baseline: 7.6566x; 7.6566x over previous
//
#include <hip/hip_runtime.h>
#include <math.h>

#define NT  256
#define SPB 84           // samples per block, 3 threads per sample (252 active)

// ---- LDS float offsets ----
#define O_REC  0      // 512:  per-h 16: A[6], Bm[6], c0, w2, pad2
#define O_WD1  512    // 192   [m][o] 6x32
#define O_BD1  704    // 32
#define O_WD2  736    // 1024  [k][o] 32x32
#define O_BD2  1760   // 32
#define O_WD3T 1792   // 192   [j][k] transposed 6x32
#define O_BD3  1984   // 8 (6 used)
#define O_WS1  1992   // 576   [m][o] 18x32
#define O_BS1  2568   // 32
#define O_WS2  2600   // 512   [k][o] 32x16
#define O_BS2  3112   // 16
#define O_WS3  3128   // 16
#define O_MISC 3144   // [0]=bs3, [1]=be2
#define W_TOT  3148

#define ADJ_STRIDE 52    // floats per sample in adj_s (6 rows x 8 + 4 pad; 52*s spreads banks)

__device__ __forceinline__ float sigmoidf_(float x) {
    return 1.0f / (1.0f + __expf(-x));
}

__global__ __launch_bounds__(NT, 1) void fused3_kernel(
        const float* __restrict__ factors,
        const float* __restrict__ Wn,  const float* __restrict__ bn,
        const float* __restrict__ We1, const float* __restrict__ be1,
        const float* __restrict__ We2, const float* __restrict__ be2,
        const float* __restrict__ Wd1, const float* __restrict__ bd1,
        const float* __restrict__ Wd2, const float* __restrict__ bd2,
        const float* __restrict__ Wd3, const float* __restrict__ bd3,
        const float* __restrict__ Ws1, const float* __restrict__ bs1,
        const float* __restrict__ Ws2, const float* __restrict__ bs2,
        const float* __restrict__ Ws3, const float* __restrict__ bs3,
        float* __restrict__ adj_out, float* __restrict__ pred_out,
        float* __restrict__ scores, int B) {
    __shared__ float Wsh[W_TOT];
    __shared__ float adj_s[SPB * ADJ_STRIDE];
    __shared__ float sc_s[SPB * 6];

    const int t = threadIdx.x;
    const int s = t / 3;           // sample slot 0..84 (85 for t=255, clamped below)
    const int n = t - s * 3;       // this thread owns rows n and n+3
    const int b = blockIdx.x * SPB + s;
    const bool act = (t < SPB * 3);             // 252 active
    const int sl_ = (s < SPB) ? s : (SPB - 1);  // clamped LDS slot for inactive lanes
    const bool bv = act && (b < B);

    // ---- factor prefetch (registers) ----
    float fall[36], fi0[6], fi1[6];
    #pragma unroll
    for (int q = 0; q < 36; ++q) fall[q] = 0.f;
    #pragma unroll
    for (int m = 0; m < 6; ++m) { fi0[m] = 0.f; fi1[m] = 0.f; }
    if (bv) {
        const float* f = factors + (size_t)b * 36;
        #pragma unroll
        for (int q = 0; q < 9; ++q) {
            float4 v = reinterpret_cast<const float4*>(f)[q];
            fall[q*4+0] = v.x; fall[q*4+1] = v.y; fall[q*4+2] = v.z; fall[q*4+3] = v.w;
        }
        const float* fr0 = f + n * 6;        // row n
        const float* fr1 = fr0 + 18;         // row n+3
        #pragma unroll
        for (int q = 0; q < 3; ++q) {
            float2 v0 = reinterpret_cast<const float2*>(fr0)[q];
            float2 v1 = reinterpret_cast<const float2*>(fr1)[q];
            fi0[q*2+0] = v0.x; fi0[q*2+1] = v0.y;
            fi1[q*2+0] = v1.x; fi1[q*2+1] = v1.y;
        }
    }

    // ---- inline fold: rec[512] into LDS ----
    #pragma unroll
    for (int e0 = 0; e0 < 512; e0 += NT) {
        int e = e0 + t;
        int h = e >> 4, sl = e & 15;
        float val = 0.0f;
        if (sl < 6) {
            #pragma unroll
            for (int k = 0; k < 32; ++k) val = fmaf(Wn[sl*32+k], We1[k*32+h], val);
        } else if (sl < 12) {
            int m = sl - 6;
            #pragma unroll
            for (int k = 0; k < 32; ++k) val = fmaf(Wn[m*32+k], We1[(32+k)*32+h], val);
        } else if (sl == 12) {
            #pragma unroll
            for (int k = 0; k < 32; ++k) val = fmaf(bn[k], We1[k*32+h] + We1[(32+k)*32+h], val);
            val += be1[h];
        } else if (sl == 13) {
            val = We2[h];
        }
        Wsh[O_REC + e] = val;
    }
    // ---- stage dyn/scorer weights ----
    for (int i = t; i < 192;  i += NT) Wsh[O_WD1 + i] = Wd1[i];
    for (int i = t; i < 1024; i += NT) Wsh[O_WD2 + i] = Wd2[i];
    for (int i = t; i < 192;  i += NT) { int j = i >> 5, k = i & 31; Wsh[O_WD3T + i] = Wd3[k*6 + j]; }
    for (int i = t; i < 576;  i += NT) Wsh[O_WS1 + i] = Ws1[i];
    for (int i = t; i < 512;  i += NT) Wsh[O_WS2 + i] = Ws2[i];
    if (t < 32) Wsh[O_BD1 + t] = bd1[t];
    if (t < 32) Wsh[O_BD2 + t] = bd2[t];
    if (t < 6)  Wsh[O_BD3 + t] = bd3[t];
    if (t < 32) Wsh[O_BS1 + t] = bs1[t];
    if (t < 16) Wsh[O_BS2 + t] = bs2[t];
    if (t < 16) Wsh[O_WS3 + t] = Ws3[t];
    if (t == 0) { Wsh[O_MISC] = bs3[0]; Wsh[O_MISC + 1] = be2[0]; }
    __syncthreads();

    // ================= edge phase (rows n and n+3, vj shared) =================
    float av0[6], av1[6];
    {
        float acc0[6] = {0.f,0.f,0.f,0.f,0.f,0.f};
        float acc1[6] = {0.f,0.f,0.f,0.f,0.f,0.f};
        #pragma unroll 2
        for (int h = 0; h < 32; ++h) {
            const float* r = &Wsh[O_REC + (h << 4)];
            const float4 r0 = *reinterpret_cast<const float4*>(&r[0]);
            const float4 r1 = *reinterpret_cast<const float4*>(&r[4]);
            const float4 r2 = *reinterpret_cast<const float4*>(&r[8]);
            const float4 r3 = *reinterpret_cast<const float4*>(&r[12]);
            float uh0 = r3.x, uh1 = r3.x;
            uh0 = fmaf(fi0[0], r0.x, uh0); uh1 = fmaf(fi1[0], r0.x, uh1);
            uh0 = fmaf(fi0[1], r0.y, uh0); uh1 = fmaf(fi1[1], r0.y, uh1);
            uh0 = fmaf(fi0[2], r0.z, uh0); uh1 = fmaf(fi1[2], r0.z, uh1);
            uh0 = fmaf(fi0[3], r0.w, uh0); uh1 = fmaf(fi1[3], r0.w, uh1);
            uh0 = fmaf(fi0[4], r1.x, uh0); uh1 = fmaf(fi1[4], r1.x, uh1);
            uh0 = fmaf(fi0[5], r1.y, uh0); uh1 = fmaf(fi1[5], r1.y, uh1);
            const float w2 = r3.y;
            #pragma unroll
            for (int j = 0; j < 6; ++j) {
                float vj =      fall[j*6+0] * r1.z;
                vj = fmaf(fall[j*6+1], r1.w, vj);
                vj = fmaf(fall[j*6+2], r2.x, vj);
                vj = fmaf(fall[j*6+3], r2.y, vj);
                vj = fmaf(fall[j*6+4], r2.z, vj);
                vj = fmaf(fall[j*6+5], r2.w, vj);
                acc0[j] = fmaf(fmaxf(uh0 + vj, 0.f), w2, acc0[j]);
                acc1[j] = fmaf(fmaxf(uh1 + vj, 0.f), w2, acc1[j]);
            }
        }
        const float b2 = Wsh[O_MISC + 1];
        #pragma unroll
        for (int j = 0; j < 6; ++j) {
            av0[j] = (j == n)     ? 0.f : sigmoidf_(acc0[j] + b2);
            av1[j] = (j == n + 3) ? 0.f : sigmoidf_(acc1[j] + b2);
        }
    }
    if (act) {
        float* as = &adj_s[sl_ * ADJ_STRIDE];
        *reinterpret_cast<float4*>(&as[n*8])       = make_float4(av0[0], av0[1], av0[2], av0[3]);
        *reinterpret_cast<float2*>(&as[n*8+4])     = make_float2(av0[4], av0[5]);
        *reinterpret_cast<float4*>(&as[(n+3)*8])   = make_float4(av1[0], av1[1], av1[2], av1[3]);
        *reinterpret_cast<float2*>(&as[(n+3)*8+4]) = make_float2(av1[4], av1[5]);
    }
    if (bv) {
        float* ao = adj_out + (size_t)b * 36 + n * 6;
        *reinterpret_cast<float2*>(&ao[0])  = make_float2(av0[0], av0[1]);
        *reinterpret_cast<float2*>(&ao[2])  = make_float2(av0[2], av0[3]);
        *reinterpret_cast<float2*>(&ao[4])  = make_float2(av0[4], av0[5]);
        *reinterpret_cast<float2*>(&ao[18]) = make_float2(av1[0], av1[1]);
        *reinterpret_cast<float2*>(&ao[20]) = make_float2(av1[2], av1[3]);
        *reinterpret_cast<float2*>(&ao[22]) = make_float2(av1[4], av1[5]);
    }
    __syncthreads();

    // ================= dynamics (rows n, n+3) =================
    float pra[6], prb[6];
    float h2a[32], h2b[32];
    {
        float st0[6], st1[6];
        {
            const float* as = &adj_s[sl_ * ADJ_STRIDE];
            #pragma unroll
            for (int i = 0; i < 6; ++i) {
                const float4 qa = *reinterpret_cast<const float4*>(&as[i*8]);
                const float2 qb = *reinterpret_cast<const float2*>(&as[i*8+4]);
                float v = fi0[0] * qa.x;
                v = fmaf(fi0[1], qa.y, v); v = fmaf(fi0[2], qa.z, v);
                v = fmaf(fi0[3], qa.w, v); v = fmaf(fi0[4], qb.x, v);
                v = fmaf(fi0[5], qb.y, v);
                st0[i] = v;
                float w = fi1[0] * qa.x;
                w = fmaf(fi1[1], qa.y, w); w = fmaf(fi1[2], qa.z, w);
                w = fmaf(fi1[3], qa.w, w); w = fmaf(fi1[4], qb.x, w);
                w = fmaf(fi1[5], qb.y, w);
                st1[i] = w;
            }
        }

        // h1 = relu(st @ Wd1 + bd1), both rows
        float h1a[32], h1b[32];
        #pragma unroll
        for (int o4 = 0; o4 < 8; ++o4) {
            const float4 v = *reinterpret_cast<const float4*>(&Wsh[O_BD1 + o4*4]);
            h1a[o4*4+0] = v.x; h1a[o4*4+1] = v.y; h1a[o4*4+2] = v.z; h1a[o4*4+3] = v.w;
            h1b[o4*4+0] = v.x; h1b[o4*4+1] = v.y; h1b[o4*4+2] = v.z; h1b[o4*4+3] = v.w;
        }
        #pragma unroll
        for (int m = 0; m < 6; ++m) {
            const float sa = st0[m], sb = st1[m];
            #pragma unroll
            for (int o4 = 0; o4 < 8; ++o4) {
                const float4 w = *reinterpret_cast<const float4*>(&Wsh[O_WD1 + m*32 + o4*4]);
                h1a[o4*4+0] = fmaf(sa, w.x, h1a[o4*4+0]); h1b[o4*4+0] = fmaf(sb, w.x, h1b[o4*4+0]);
                h1a[o4*4+1] = fmaf(sa, w.y, h1a[o4*4+1]); h1b[o4*4+1] = fmaf(sb, w.y, h1b[o4*4+1]);
                h1a[o4*4+2] = fmaf(sa, w.z, h1a[o4*4+2]); h1b[o4*4+2] = fmaf(sb, w.z, h1b[o4*4+2]);
                h1a[o4*4+3] = fmaf(sa, w.w, h1a[o4*4+3]); h1b[o4*4+3] = fmaf(sb, w.w, h1b[o4*4+3]);
            }
        }
        #pragma unroll
        for (int o = 0; o < 32; ++o) { h1a[o] = fmaxf(h1a[o], 0.f); h1b[o] = fmaxf(h1b[o], 0.f); }

        // h2 = relu(h1 @ Wd2 + bd2)
        #pragma unroll
        for (int o4 = 0; o4 < 8; ++o4) {
            const float4 v = *reinterpret_cast<const float4*>(&Wsh[O_BD2 + o4*4]);
            h2a[o4*4+0] = v.x; h2a[o4*4+1] = v.y; h2a[o4*4+2] = v.z; h2a[o4*4+3] = v.w;
            h2b[o4*4+0] = v.x; h2b[o4*4+1] = v.y; h2b[o4*4+2] = v.z; h2b[o4*4+3] = v.w;
        }
        #pragma unroll
        for (int k = 0; k < 32; ++k) {
            const float xa = h1a[k], xb = h1b[k];
            #pragma unroll
            for (int o4 = 0; o4 < 8; ++o4) {
                const float4 w = *reinterpret_cast<const float4*>(&Wsh[O_WD2 + k*32 + o4*4]);
                h2a[o4*4+0] = fmaf(xa, w.x, h2a[o4*4+0]); h2b[o4*4+0] = fmaf(xb, w.x, h2b[o4*4+0]);
                h2a[o4*4+1] = fmaf(xa, w.y, h2a[o4*4+1]); h2b[o4*4+1] = fmaf(xb, w.y, h2b[o4*4+1]);
                h2a[o4*4+2] = fmaf(xa, w.z, h2a[o4*4+2]); h2b[o4*4+2] = fmaf(xb, w.z, h2b[o4*4+2]);
                h2a[o4*4+3] = fmaf(xa, w.w, h2a[o4*4+3]); h2b[o4*4+3] = fmaf(xb, w.w, h2b[o4*4+3]);
            }
        }
        #pragma unroll
        for (int o = 0; o < 32; ++o) { h2a[o] = fmaxf(h2a[o], 0.f); h2b[o] = fmaxf(h2b[o], 0.f); }
    }

    // pred = h2 @ Wd3 + bd3 (Wd3T [j][k])
    #pragma unroll
    for (int j = 0; j < 6; ++j) {
        float va = Wsh[O_BD3 + j], vb = va;
        #pragma unroll
        for (int k4 = 0; k4 < 8; ++k4) {
            const float4 w = *reinterpret_cast<const float4*>(&Wsh[O_WD3T + j*32 + k4*4]);
            va = fmaf(h2a[k4*4+0], w.x, va); vb = fmaf(h2b[k4*4+0], w.x, vb);
            va = fmaf(h2a[k4*4+1], w.y, va); vb = fmaf(h2b[k4*4+1], w.y, vb);
            va = fmaf(h2a[k4*4+2], w.z, va); vb = fmaf(h2b[k4*4+2], w.z, vb);
            va = fmaf(h2a[k4*4+3], w.w, va); vb = fmaf(h2b[k4*4+3], w.w, vb);
        }
        pra[j] = va; prb[j] = vb;
    }
    if (bv) {
        float* po = pred_out + (size_t)b * 36 + n * 6;
        *reinterpret_cast<float2*>(&po[0])  = make_float2(pra[0], pra[1]);
        *reinterpret_cast<float2*>(&po[2])  = make_float2(pra[2], pra[3]);
        *reinterpret_cast<float2*>(&po[4])  = make_float2(pra[4], pra[5]);
        *reinterpret_cast<float2*>(&po[18]) = make_float2(prb[0], prb[1]);
        *reinterpret_cast<float2*>(&po[20]) = make_float2(prb[2], prb[3]);
        *reinterpret_cast<float2*>(&po[22]) = make_float2(prb[4], prb[5]);
    }

    // ================= scorer (rows n, n+3) =================
    {
        float dfa[6], dfb[6];
        #pragma unroll
        for (int j = 0; j < 6; ++j) { dfa[j] = fabsf(fi0[j] - pra[j]); dfb[j] = fabsf(fi1[j] - prb[j]); }

        float s1a[32], s1b[32];
        #pragma unroll
        for (int o4 = 0; o4 < 8; ++o4) {
            const float4 v = *reinterpret_cast<const float4*>(&Wsh[O_BS1 + o4*4]);
            s1a[o4*4+0] = v.x; s1a[o4*4+1] = v.y; s1a[o4*4+2] = v.z; s1a[o4*4+3] = v.w;
            s1b[o4*4+0] = v.x; s1b[o4*4+1] = v.y; s1b[o4*4+2] = v.z; s1b[o4*4+3] = v.w;
        }
        #pragma unroll
        for (int m = 0; m < 6; ++m) {
            const float aa = fi0[m], pa = pra[m], da = dfa[m];
            const float ab = fi1[m], pb = prb[m], db = dfb[m];
            #pragma unroll
            for (int o4 = 0; o4 < 8; ++o4) {
                const float4 wa = *reinterpret_cast<const float4*>(&Wsh[O_WS1 + m*32 + o4*4]);
                const float4 wp = *reinterpret_cast<const float4*>(&Wsh[O_WS1 + (6+m)*32 + o4*4]);
                const float4 wd = *reinterpret_cast<const float4*>(&Wsh[O_WS1 + (12+m)*32 + o4*4]);
                s1a[o4*4+0] = fmaf(aa, wa.x, fmaf(pa, wp.x, fmaf(da, wd.x, s1a[o4*4+0])));
                s1b[o4*4+0] = fmaf(ab, wa.x, fmaf(pb, wp.x, fmaf(db, wd.x, s1b[o4*4+0])));
                s1a[o4*4+1] = fmaf(aa, wa.y, fmaf(pa, wp.y, fmaf(da, wd.y, s1a[o4*4+1])));
                s1b[o4*4+1] = fmaf(ab, wa.y, fmaf(pb, wp.y, fmaf(db, wd.y, s1b[o4*4+1])));
                s1a[o4*4+2] = fmaf(aa, wa.z, fmaf(pa, wp.z, fmaf(da, wd.z, s1a[o4*4+2])));
                s1b[o4*4+2] = fmaf(ab, wa.z, fmaf(pb, wp.z, fmaf(db, wd.z, s1b[o4*4+2])));
                s1a[o4*4+3] = fmaf(aa, wa.w, fmaf(pa, wp.w, fmaf(da, wd.w, s1a[o4*4+3])));
                s1b[o4*4+3] = fmaf(ab, wa.w, fmaf(pb, wp.w, fmaf(db, wd.w, s1b[o4*4+3])));
            }
        }
        #pragma unroll
        for (int o = 0; o < 32; ++o) { s1a[o] = fmaxf(s1a[o], 0.f); s1b[o] = fmaxf(s1b[o], 0.f); }

        float s2a[16], s2b[16];
        #pragma unroll
        for (int o4 = 0; o4 < 4; ++o4) {
            const float4 v = *reinterpret_cast<const float4*>(&Wsh[O_BS2 + o4*4]);
            s2a[o4*4+0] = v.x; s2a[o4*4+1] = v.y; s2a[o4*4+2] = v.z; s2a[o4*4+3] = v.w;
            s2b[o4*4+0] = v.x; s2b[o4*4+1] = v.y; s2b[o4*4+2] = v.z; s2b[o4*4+3] = v.w;
        }
        #pragma unroll
        for (int k = 0; k < 32; ++k) {
            const float xa = s1a[k], xb = s1b[k];
            #pragma unroll
            for (int o4 = 0; o4 < 4; ++o4) {
                const float4 w = *reinterpret_cast<const float4*>(&Wsh[O_WS2 + k*16 + o4*4]);
                s2a[o4*4+0] = fmaf(xa, w.x, s2a[o4*4+0]); s2b[o4*4+0] = fmaf(xb, w.x, s2b[o4*4+0]);
                s2a[o4*4+1] = fmaf(xa, w.y, s2a[o4*4+1]); s2b[o4*4+1] = fmaf(xb, w.y, s2b[o4*4+1]);
                s2a[o4*4+2] = fmaf(xa, w.z, s2a[o4*4+2]); s2b[o4*4+2] = fmaf(xb, w.z, s2b[o4*4+2]);
                s2a[o4*4+3] = fmaf(xa, w.w, s2a[o4*4+3]); s2b[o4*4+3] = fmaf(xb, w.w, s2b[o4*4+3]);
            }
        }
        #pragma unroll
        for (int o = 0; o < 16; ++o) { s2a[o] = fmaxf(s2a[o], 0.f); s2b[o] = fmaxf(s2b[o], 0.f); }

        float s3a = Wsh[O_MISC], s3b = s3a;
        #pragma unroll
        for (int k4 = 0; k4 < 4; ++k4) {
            const float4 w = *reinterpret_cast<const float4*>(&Wsh[O_WS3 + k4*4]);
            s3a = fmaf(s2a[k4*4+0], w.x, s3a); s3b = fmaf(s2b[k4*4+0], w.x, s3b);
            s3a = fmaf(s2a[k4*4+1], w.y, s3a); s3b = fmaf(s2b[k4*4+1], w.y, s3b);
            s3a = fmaf(s2a[k4*4+2], w.z, s3a); s3b = fmaf(s2b[k4*4+2], w.z, s3b);
            s3a = fmaf(s2a[k4*4+3], w.w, s3a); s3b = fmaf(s2b[k4*4+3], w.w, s3b);
        }
        if (act) {
            sc_s[sl_*6 + n]     = sigmoidf_(s3a);
            sc_s[sl_*6 + n + 3] = sigmoidf_(s3b);
        }
    }
    __syncthreads();

    if (bv && n == 0) {
        float sum = sc_s[sl_*6+0] + sc_s[sl_*6+1] + sc_s[sl_*6+2]
                  + sc_s[sl_*6+3] + sc_s[sl_*6+4] + sc_s[sl_*6+5];
        scores[b] = sum * (1.0f / 6.0f);
    }
}

extern "C" void kernel_launch(void* const* d_in, const int* in_sizes, int n_in,
                              void* d_out, int out_size, void* d_ws, size_t ws_size,
                              hipStream_t stream) {
    const float* factors = (const float*)d_in[0];
    const float* Wn  = (const float*)d_in[1];
    const float* bn  = (const float*)d_in[2];
    const float* We1 = (const float*)d_in[3];
    const float* be1 = (const float*)d_in[4];
    const float* We2 = (const float*)d_in[5];
    const float* be2 = (const float*)d_in[6];
    const float* Wd1 = (const float*)d_in[7];
    const float* bd1 = (const float*)d_in[8];
    const float* Wd2 = (const float*)d_in[9];
    const float* bd2 = (const float*)d_in[10];
    const float* Wd3 = (const float*)d_in[11];
    const float* bd3 = (const float*)d_in[12];
    const float* Ws1 = (const float*)d_in[13];
    const float* bs1 = (const float*)d_in[14];
    const float* Ws2 = (const float*)d_in[15];
    const float* bs2 = (const float*)d_in[16];
    const float* Ws3 = (const float*)d_in[17];
    const float* bs3 = (const float*)d_in[18];

    int B = in_sizes[0] / 36;

    float* adj_out  = (float*)d_out;                       // [B,6,6]
    float* pred_out = (float*)d_out + (size_t)B * 36;      // [B,6,6]
    float* scores   = (float*)d_out + (size_t)B * 72;      // [B]

    int nblocks = (B + SPB - 1) / SPB;
    hipLaunchKernelGGL(fused3_kernel, dim3(nblocks), dim3(NT), 0, stream,
                       factors, Wn, bn, We1, be1, We2, be2,
                       Wd1, bd1, Wd2, bd2, Wd3, bd3,
                       Ws1, bs1, Ws2, bs2, Ws3, bs3,
                       adj_out, pred_out, scores, B);
}

// Round 5
// 160.700 us; speedup vs baseline: 8.5641x; 1.1185x over previous
//
#include <hip/hip_runtime.h>
#include <math.h>

#define NT  256
#define SPB 42          // samples per block, 6 threads (rows) per sample: 252 active

// ---- cat / LDS float offsets (all %4==0) ----
#define O_REC  0      // 512:  per-h 16: A[6], Bm[6], c0, w2, pad2
#define O_WD1  512    // 192   [m][o] 6x32
#define O_BD1  704    // 32
#define O_WD2  736    // 1024  [k][o] 32x32
#define O_BD2  1760   // 32
#define O_WD3T 1792   // 192   [j][k] transposed 6x32
#define O_BD3  1984   // 8 (6 used)
#define O_WS1  1992   // 576   [m][o] 18x32
#define O_BS1  2568   // 32
#define O_WS2  2600   // 512   [k][o] 32x16
#define O_BS2  3112   // 16
#define O_WS3  3128   // 16
#define O_MISC 3144   // [0]=bs3, [1]=be2, rest pad
#define W_TOT  3152

#define ADJ_STRIDE 52   // 52%32=20 -> good bank spread; 52%4==0 keeps float4 align

__device__ __forceinline__ float sigmoidf_(float x) {
    return 1.0f / (1.0f + __expf(-x));
}

// Single block, 512 threads: fold edge-predictor weights + pack ALL weights
// (with Wd3 transposed) into cat[3152] in d_ws.
__global__ __launch_bounds__(512) void fold_kernel(
        const float* __restrict__ Wn,  const float* __restrict__ bn,
        const float* __restrict__ We1, const float* __restrict__ be1,
        const float* __restrict__ We2, const float* __restrict__ be2,
        const float* __restrict__ Wd1, const float* __restrict__ bd1,
        const float* __restrict__ Wd2, const float* __restrict__ bd2,
        const float* __restrict__ Wd3, const float* __restrict__ bd3,
        const float* __restrict__ Ws1, const float* __restrict__ bs1,
        const float* __restrict__ Ws2, const float* __restrict__ bs2,
        const float* __restrict__ Ws3, const float* __restrict__ bs3,
        float* __restrict__ cat) {
    const int t = threadIdx.x;
    // rec[512]: per h (t>>4), slot (t&15)
    {
        const int h = t >> 4, sl = t & 15;
        float val = 0.0f;
        if (sl < 6) {
            #pragma unroll
            for (int k = 0; k < 32; ++k) val = fmaf(Wn[sl*32+k], We1[k*32+h], val);
        } else if (sl < 12) {
            const int m = sl - 6;
            #pragma unroll
            for (int k = 0; k < 32; ++k) val = fmaf(Wn[m*32+k], We1[(32+k)*32+h], val);
        } else if (sl == 12) {
            #pragma unroll
            for (int k = 0; k < 32; ++k) val = fmaf(bn[k], We1[k*32+h] + We1[(32+k)*32+h], val);
            val += be1[h];
        } else if (sl == 13) {
            val = We2[h];
        }
        cat[t] = val;
    }
    for (int i = 512 + t; i < W_TOT; i += 512) {
        float v = 0.0f;
        if      (i < O_BD1)  v = Wd1[i - O_WD1];
        else if (i < O_WD2)  v = bd1[i - O_BD1];
        else if (i < O_BD2)  v = Wd2[i - O_WD2];
        else if (i < O_WD3T) v = bd2[i - O_BD2];
        else if (i < O_BD3)  { int q = i - O_WD3T; v = Wd3[(q & 31) * 6 + (q >> 5)]; }
        else if (i < O_WS1)  { int q = i - O_BD3; v = (q < 6) ? bd3[q] : 0.0f; }
        else if (i < O_BS1)  v = Ws1[i - O_WS1];
        else if (i < O_WS2)  v = bs1[i - O_BS1];
        else if (i < O_BS2)  v = Ws2[i - O_WS2];
        else if (i < O_WS3)  v = bs2[i - O_BS2];
        else if (i < O_MISC) v = Ws3[i - O_WS3];
        else { int q = i - O_MISC; v = (q == 0) ? bs3[0] : ((q == 1) ? be2[0] : 0.0f); }
        cat[i] = v;
    }
}

__global__ __launch_bounds__(NT, 2) void fused4_kernel(
        const float* __restrict__ factors, const float* __restrict__ cat,
        float* __restrict__ adj_out, float* __restrict__ pred_out,
        float* __restrict__ scores, int B) {
    __shared__ __align__(16) float Wsh[W_TOT];
    __shared__ __align__(16) float adj_s[SPB * ADJ_STRIDE];
    __shared__ float sc_s[SPB * 6];

    const int t = threadIdx.x;
    // ---- stage cat -> LDS, coalesced float4 ----
    #pragma unroll
    for (int i0 = 0; i0 < W_TOT; i0 += NT * 4) {
        const int i = i0 + t * 4;
        if (i < W_TOT)
            *reinterpret_cast<float4*>(&Wsh[i]) = *reinterpret_cast<const float4*>(&cat[i]);
    }

    const int s = t / 6;
    const int n = t - s * 6;
    const int b = blockIdx.x * SPB + s;
    const bool act = (t < SPB * 6);
    const bool bv = act && (b < B);
    const int sl_ = (s < SPB) ? s : (SPB - 1);

    float fall[36], fi[6];
    #pragma unroll
    for (int q = 0; q < 36; ++q) fall[q] = 0.0f;
    #pragma unroll
    for (int m = 0; m < 6; ++m) fi[m] = 0.0f;
    if (bv) {
        const float* f = factors + (size_t)b * 36;
        #pragma unroll
        for (int q = 0; q < 9; ++q) {
            const float4 v = reinterpret_cast<const float4*>(f)[q];
            fall[q*4+0] = v.x; fall[q*4+1] = v.y; fall[q*4+2] = v.z; fall[q*4+3] = v.w;
        }
        const float* fr = f + n * 6;
        #pragma unroll
        for (int q = 0; q < 3; ++q) {
            const float2 v = reinterpret_cast<const float2*>(fr)[q];
            fi[q*2+0] = v.x; fi[q*2+1] = v.y;
        }
    }
    __syncthreads();

    // ================= edge phase: depth-2 pipelined over h =================
    float av[6];
    {
        float acc[6] = {0.f,0.f,0.f,0.f,0.f,0.f};
        float4 rA0 = *reinterpret_cast<const float4*>(&Wsh[O_REC + 0]);
        float4 rA1 = *reinterpret_cast<const float4*>(&Wsh[O_REC + 4]);
        float4 rA2 = *reinterpret_cast<const float4*>(&Wsh[O_REC + 8]);
        float4 rA3 = *reinterpret_cast<const float4*>(&Wsh[O_REC + 12]);
        float4 rB0 = *reinterpret_cast<const float4*>(&Wsh[O_REC + 16]);
        float4 rB1 = *reinterpret_cast<const float4*>(&Wsh[O_REC + 20]);
        float4 rB2 = *reinterpret_cast<const float4*>(&Wsh[O_REC + 24]);
        float4 rB3 = *reinterpret_cast<const float4*>(&Wsh[O_REC + 28]);
        #pragma unroll 4
        for (int h = 0; h < 32; ++h) {
            const int hn = (h + 2 < 32) ? (h + 2) : h;
            const float4 rC0 = *reinterpret_cast<const float4*>(&Wsh[O_REC + hn*16 + 0]);
            const float4 rC1 = *reinterpret_cast<const float4*>(&Wsh[O_REC + hn*16 + 4]);
            const float4 rC2 = *reinterpret_cast<const float4*>(&Wsh[O_REC + hn*16 + 8]);
            const float4 rC3 = *reinterpret_cast<const float4*>(&Wsh[O_REC + hn*16 + 12]);
            float uh = rA3.x;
            uh = fmaf(fi[0], rA0.x, uh); uh = fmaf(fi[1], rA0.y, uh);
            uh = fmaf(fi[2], rA0.z, uh); uh = fmaf(fi[3], rA0.w, uh);
            uh = fmaf(fi[4], rA1.x, uh); uh = fmaf(fi[5], rA1.y, uh);
            const float w2 = rA3.y;
            #pragma unroll
            for (int j = 0; j < 6; ++j) {
                float vj =      fall[j*6+0] * rA1.z;
                vj = fmaf(fall[j*6+1], rA1.w, vj);
                vj = fmaf(fall[j*6+2], rA2.x, vj);
                vj = fmaf(fall[j*6+3], rA2.y, vj);
                vj = fmaf(fall[j*6+4], rA2.z, vj);
                vj = fmaf(fall[j*6+5], rA2.w, vj);
                acc[j] = fmaf(fmaxf(uh + vj, 0.0f), w2, acc[j]);
            }
            rA0 = rB0; rA1 = rB1; rA2 = rB2; rA3 = rB3;
            rB0 = rC0; rB1 = rC1; rB2 = rC2; rB3 = rC3;
        }
        const float b2 = Wsh[O_MISC + 1];
        #pragma unroll
        for (int j = 0; j < 6; ++j) av[j] = (j == n) ? 0.0f : sigmoidf_(acc[j] + b2);
    }
    if (act) {
        float* as = &adj_s[sl_ * ADJ_STRIDE + n * 8];
        *reinterpret_cast<float4*>(&as[0]) = make_float4(av[0], av[1], av[2], av[3]);
        *reinterpret_cast<float2*>(&as[4]) = make_float2(av[4], av[5]);
    }
    if (bv) {
        float* ao = adj_out + (size_t)b * 36 + n * 6;
        *reinterpret_cast<float2*>(&ao[0]) = make_float2(av[0], av[1]);
        *reinterpret_cast<float2*>(&ao[2]) = make_float2(av[2], av[3]);
        *reinterpret_cast<float2*>(&ao[4]) = make_float2(av[4], av[5]);
    }
    __syncthreads();

    // ================= structured =================
    float st[6];
    {
        const float* as = &adj_s[sl_ * ADJ_STRIDE];
        #pragma unroll
        for (int i = 0; i < 6; ++i) {
            const float4 qa = *reinterpret_cast<const float4*>(&as[i*8]);
            const float2 qb = *reinterpret_cast<const float2*>(&as[i*8+4]);
            float v = fi[0] * qa.x;
            v = fmaf(fi[1], qa.y, v); v = fmaf(fi[2], qa.z, v);
            v = fmaf(fi[3], qa.w, v); v = fmaf(fi[4], qb.x, v);
            v = fmaf(fi[5], qb.y, v);
            st[i] = v;
        }
    }

    // ================= h1 = relu(st @ Wd1 + bd1) =================
    float h1[32];
    #pragma unroll
    for (int o4 = 0; o4 < 8; ++o4) {
        const float4 v = *reinterpret_cast<const float4*>(&Wsh[O_BD1 + o4*4]);
        h1[o4*4+0] = v.x; h1[o4*4+1] = v.y; h1[o4*4+2] = v.z; h1[o4*4+3] = v.w;
    }
    #pragma unroll
    for (int m = 0; m < 6; ++m) {
        const float sm = st[m];
        #pragma unroll
        for (int o4 = 0; o4 < 8; ++o4) {
            const float4 w = *reinterpret_cast<const float4*>(&Wsh[O_WD1 + m*32 + o4*4]);
            h1[o4*4+0] = fmaf(sm, w.x, h1[o4*4+0]);
            h1[o4*4+1] = fmaf(sm, w.y, h1[o4*4+1]);
            h1[o4*4+2] = fmaf(sm, w.z, h1[o4*4+2]);
            h1[o4*4+3] = fmaf(sm, w.w, h1[o4*4+3]);
        }
    }
    #pragma unroll
    for (int o = 0; o < 32; ++o) h1[o] = fmaxf(h1[o], 0.0f);

    // ============ h2 = relu(h1 @ Wd2 + bd2), 2 passes, depth-2 pipeline ============
    float h2[32];
    #pragma unroll
    for (int o4 = 0; o4 < 8; ++o4) {
        const float4 v = *reinterpret_cast<const float4*>(&Wsh[O_BD2 + o4*4]);
        h2[o4*4+0] = v.x; h2[o4*4+1] = v.y; h2[o4*4+2] = v.z; h2[o4*4+3] = v.w;
    }
    #pragma unroll
    for (int pass = 0; pass < 2; ++pass) {
        const int ob = O_WD2 + pass * 16;
        float4 wA0 = *reinterpret_cast<const float4*>(&Wsh[ob + 0]);
        float4 wA1 = *reinterpret_cast<const float4*>(&Wsh[ob + 4]);
        float4 wA2 = *reinterpret_cast<const float4*>(&Wsh[ob + 8]);
        float4 wA3 = *reinterpret_cast<const float4*>(&Wsh[ob + 12]);
        float4 wB0 = *reinterpret_cast<const float4*>(&Wsh[ob + 32 + 0]);
        float4 wB1 = *reinterpret_cast<const float4*>(&Wsh[ob + 32 + 4]);
        float4 wB2 = *reinterpret_cast<const float4*>(&Wsh[ob + 32 + 8]);
        float4 wB3 = *reinterpret_cast<const float4*>(&Wsh[ob + 32 + 12]);
        #pragma unroll
        for (int k = 0; k < 32; ++k) {
            const int kn = (k + 2 < 32) ? (k + 2) : k;
            const float4 wC0 = *reinterpret_cast<const float4*>(&Wsh[ob + kn*32 + 0]);
            const float4 wC1 = *reinterpret_cast<const float4*>(&Wsh[ob + kn*32 + 4]);
            const float4 wC2 = *reinterpret_cast<const float4*>(&Wsh[ob + kn*32 + 8]);
            const float4 wC3 = *reinterpret_cast<const float4*>(&Wsh[ob + kn*32 + 12]);
            const float x = h1[k];
            h2[pass*16+ 0] = fmaf(x, wA0.x, h2[pass*16+ 0]);
            h2[pass*16+ 1] = fmaf(x, wA0.y, h2[pass*16+ 1]);
            h2[pass*16+ 2] = fmaf(x, wA0.z, h2[pass*16+ 2]);
            h2[pass*16+ 3] = fmaf(x, wA0.w, h2[pass*16+ 3]);
            h2[pass*16+ 4] = fmaf(x, wA1.x, h2[pass*16+ 4]);
            h2[pass*16+ 5] = fmaf(x, wA1.y, h2[pass*16+ 5]);
            h2[pass*16+ 6] = fmaf(x, wA1.z, h2[pass*16+ 6]);
            h2[pass*16+ 7] = fmaf(x, wA1.w, h2[pass*16+ 7]);
            h2[pass*16+ 8] = fmaf(x, wA2.x, h2[pass*16+ 8]);
            h2[pass*16+ 9] = fmaf(x, wA2.y, h2[pass*16+ 9]);
            h2[pass*16+10] = fmaf(x, wA2.z, h2[pass*16+10]);
            h2[pass*16+11] = fmaf(x, wA2.w, h2[pass*16+11]);
            h2[pass*16+12] = fmaf(x, wA3.x, h2[pass*16+12]);
            h2[pass*16+13] = fmaf(x, wA3.y, h2[pass*16+13]);
            h2[pass*16+14] = fmaf(x, wA3.z, h2[pass*16+14]);
            h2[pass*16+15] = fmaf(x, wA3.w, h2[pass*16+15]);
            wA0 = wB0; wA1 = wB1; wA2 = wB2; wA3 = wB3;
            wB0 = wC0; wB1 = wC1; wB2 = wC2; wB3 = wC3;
        }
    }
    #pragma unroll
    for (int o = 0; o < 32; ++o) h2[o] = fmaxf(h2[o], 0.0f);

    // ================= pred = h2 @ Wd3 + bd3 (Wd3T [j][k]) =================
    float pr[6];
    #pragma unroll
    for (int j = 0; j < 6; ++j) {
        float v = Wsh[O_BD3 + j];
        #pragma unroll
        for (int k4 = 0; k4 < 8; ++k4) {
            const float4 w = *reinterpret_cast<const float4*>(&Wsh[O_WD3T + j*32 + k4*4]);
            v = fmaf(h2[k4*4+0], w.x, v);
            v = fmaf(h2[k4*4+1], w.y, v);
            v = fmaf(h2[k4*4+2], w.z, v);
            v = fmaf(h2[k4*4+3], w.w, v);
        }
        pr[j] = v;
    }
    if (bv) {
        float* po = pred_out + (size_t)b * 36 + n * 6;
        *reinterpret_cast<float2*>(&po[0]) = make_float2(pr[0], pr[1]);
        *reinterpret_cast<float2*>(&po[2]) = make_float2(pr[2], pr[3]);
        *reinterpret_cast<float2*>(&po[4]) = make_float2(pr[4], pr[5]);
    }

    // ================= scorer =================
    float df[6];
    #pragma unroll
    for (int j = 0; j < 6; ++j) df[j] = fabsf(fi[j] - pr[j]);

    float s1[32];
    #pragma unroll
    for (int o4 = 0; o4 < 8; ++o4) {
        const float4 v = *reinterpret_cast<const float4*>(&Wsh[O_BS1 + o4*4]);
        s1[o4*4+0] = v.x; s1[o4*4+1] = v.y; s1[o4*4+2] = v.z; s1[o4*4+3] = v.w;
    }
    #pragma unroll
    for (int m = 0; m < 6; ++m) {
        const float a = fi[m], p = pr[m], d = df[m];
        #pragma unroll
        for (int o4 = 0; o4 < 8; ++o4) {
            const float4 wa = *reinterpret_cast<const float4*>(&Wsh[O_WS1 + m*32 + o4*4]);
            const float4 wp = *reinterpret_cast<const float4*>(&Wsh[O_WS1 + (6+m)*32 + o4*4]);
            const float4 wd = *reinterpret_cast<const float4*>(&Wsh[O_WS1 + (12+m)*32 + o4*4]);
            s1[o4*4+0] = fmaf(a, wa.x, fmaf(p, wp.x, fmaf(d, wd.x, s1[o4*4+0])));
            s1[o4*4+1] = fmaf(a, wa.y, fmaf(p, wp.y, fmaf(d, wd.y, s1[o4*4+1])));
            s1[o4*4+2] = fmaf(a, wa.z, fmaf(p, wp.z, fmaf(d, wd.z, s1[o4*4+2])));
            s1[o4*4+3] = fmaf(a, wa.w, fmaf(p, wp.w, fmaf(d, wd.w, s1[o4*4+3])));
        }
    }
    #pragma unroll
    for (int o = 0; o < 32; ++o) s1[o] = fmaxf(s1[o], 0.0f);

    // s2: depth-2 pipelined, 16 outputs, 4 float4 per k
    float s2v[16];
    #pragma unroll
    for (int o4 = 0; o4 < 4; ++o4) {
        const float4 v = *reinterpret_cast<const float4*>(&Wsh[O_BS2 + o4*4]);
        s2v[o4*4+0] = v.x; s2v[o4*4+1] = v.y; s2v[o4*4+2] = v.z; s2v[o4*4+3] = v.w;
    }
    {
        float4 wA0 = *reinterpret_cast<const float4*>(&Wsh[O_WS2 + 0]);
        float4 wA1 = *reinterpret_cast<const float4*>(&Wsh[O_WS2 + 4]);
        float4 wA2 = *reinterpret_cast<const float4*>(&Wsh[O_WS2 + 8]);
        float4 wA3 = *reinterpret_cast<const float4*>(&Wsh[O_WS2 + 12]);
        float4 wB0 = *reinterpret_cast<const float4*>(&Wsh[O_WS2 + 16 + 0]);
        float4 wB1 = *reinterpret_cast<const float4*>(&Wsh[O_WS2 + 16 + 4]);
        float4 wB2 = *reinterpret_cast<const float4*>(&Wsh[O_WS2 + 16 + 8]);
        float4 wB3 = *reinterpret_cast<const float4*>(&Wsh[O_WS2 + 16 + 12]);
        #pragma unroll
        for (int k = 0; k < 32; ++k) {
            const int kn = (k + 2 < 32) ? (k + 2) : k;
            const float4 wC0 = *reinterpret_cast<const float4*>(&Wsh[O_WS2 + kn*16 + 0]);
            const float4 wC1 = *reinterpret_cast<const float4*>(&Wsh[O_WS2 + kn*16 + 4]);
            const float4 wC2 = *reinterpret_cast<const float4*>(&Wsh[O_WS2 + kn*16 + 8]);
            const float4 wC3 = *reinterpret_cast<const float4*>(&Wsh[O_WS2 + kn*16 + 12]);
            const float x = s1[k];
            s2v[ 0] = fmaf(x, wA0.x, s2v[ 0]);
            s2v[ 1] = fmaf(x, wA0.y, s2v[ 1]);
            s2v[ 2] = fmaf(x, wA0.z, s2v[ 2]);
            s2v[ 3] = fmaf(x, wA0.w, s2v[ 3]);
            s2v[ 4] = fmaf(x, wA1.x, s2v[ 4]);
            s2v[ 5] = fmaf(x, wA1.y, s2v[ 5]);
            s2v[ 6] = fmaf(x, wA1.z, s2v[ 6]);
            s2v[ 7] = fmaf(x, wA1.w, s2v[ 7]);
            s2v[ 8] = fmaf(x, wA2.x, s2v[ 8]);
            s2v[ 9] = fmaf(x, wA2.y, s2v[ 9]);
            s2v[10] = fmaf(x, wA2.z, s2v[10]);
            s2v[11] = fmaf(x, wA2.w, s2v[11]);
            s2v[12] = fmaf(x, wA3.x, s2v[12]);
            s2v[13] = fmaf(x, wA3.y, s2v[13]);
            s2v[14] = fmaf(x, wA3.z, s2v[14]);
            s2v[15] = fmaf(x, wA3.w, s2v[15]);
            wA0 = wB0; wA1 = wB1; wA2 = wB2; wA3 = wB3;
            wB0 = wC0; wB1 = wC1; wB2 = wC2; wB3 = wC3;
        }
    }
    #pragma unroll
    for (int o = 0; o < 16; ++o) s2v[o] = fmaxf(s2v[o], 0.0f);

    float s3 = Wsh[O_MISC];
    #pragma unroll
    for (int k4 = 0; k4 < 4; ++k4) {
        const float4 w = *reinterpret_cast<const float4*>(&Wsh[O_WS3 + k4*4]);
        s3 = fmaf(s2v[k4*4+0], w.x, s3);
        s3 = fmaf(s2v[k4*4+1], w.y, s3);
        s3 = fmaf(s2v[k4*4+2], w.z, s3);
        s3 = fmaf(s2v[k4*4+3], w.w, s3);
    }
    if (act) sc_s[sl_ * 6 + n] = sigmoidf_(s3);
    __syncthreads();

    if (bv && n == 0) {
        const float sum = sc_s[sl_*6+0] + sc_s[sl_*6+1] + sc_s[sl_*6+2]
                        + sc_s[sl_*6+3] + sc_s[sl_*6+4] + sc_s[sl_*6+5];
        scores[b] = sum * (1.0f / 6.0f);
    }
}

extern "C" void kernel_launch(void* const* d_in, const int* in_sizes, int n_in,
                              void* d_out, int out_size, void* d_ws, size_t ws_size,
                              hipStream_t stream) {
    const float* factors = (const float*)d_in[0];
    const float* Wn  = (const float*)d_in[1];
    const float* bn  = (const float*)d_in[2];
    const float* We1 = (const float*)d_in[3];
    const float* be1 = (const float*)d_in[4];
    const float* We2 = (const float*)d_in[5];
    const float* be2 = (const float*)d_in[6];
    const float* Wd1 = (const float*)d_in[7];
    const float* bd1 = (const float*)d_in[8];
    const float* Wd2 = (const float*)d_in[9];
    const float* bd2 = (const float*)d_in[10];
    const float* Wd3 = (const float*)d_in[11];
    const float* bd3 = (const float*)d_in[12];
    const float* Ws1 = (const float*)d_in[13];
    const float* bs1 = (const float*)d_in[14];
    const float* Ws2 = (const float*)d_in[15];
    const float* bs2 = (const float*)d_in[16];
    const float* Ws3 = (const float*)d_in[17];
    const float* bs3 = (const float*)d_in[18];

    const int B = in_sizes[0] / 36;

    float* adj_out  = (float*)d_out;                       // [B,6,6]
    float* pred_out = (float*)d_out + (size_t)B * 36;      // [B,6,6]
    float* scores   = (float*)d_out + (size_t)B * 72;      // [B]
    float* cat      = (float*)d_ws;                        // 3152 floats

    hipLaunchKernelGGL(fold_kernel, dim3(1), dim3(512), 0, stream,
                       Wn, bn, We1, be1, We2, be2,
                       Wd1, bd1, Wd2, bd2, Wd3, bd3,
                       Ws1, bs1, Ws2, bs2, Ws3, bs3, cat);

    const int nblocks = (B + SPB - 1) / SPB;
    hipLaunchKernelGGL(fused4_kernel, dim3(nblocks), dim3(NT), 0, stream,
                       factors, cat, adj_out, pred_out, scores, B);
}